// Round 13
// baseline (91.982 us; speedup 1.0000x reference)
//
#include <hip/hip_runtime.h>
#include <math.h>

// critic_attention, round 13: SWAPPED phase-A MFMA (T12 trick: reduction axis
// lane-local). Compute H^T = W0^T x X^T instead of X x W0. A/B fragment
// layouts are lane-identical on gfx950, so the same ws fragments and input
// registers work - only the MFMA operand order changes. D now: col = item
// (l&15), row = channel (cb*16 + lg*4 + reg). Each lane owns ONE item's 16
// channels:
//   - W1 dot: 16 local fma + 2 shfl (was 4 fma + 16 shfl, 4-deep)
//   - softmax scalars (lrelu/exp2/s): 1 per lane (was 4)
//   - tanh / xsum / MFMA counts unchanged
// Rest = round-12 structure: 2-wave block, agent-split, LDS merge, col-split
// phase B, pre-split fp16 hi/lo weights in ws.
//
// ws layout (halfs): W0h@0[2][4][4][16][8] W0l@4096 | W2h@8192[4][8][4][16][8]
//   W2l@24576 | W3h@40960 W3l@57344.  Total 73728 halfs = 147456 B.

#define SLOPE 0.01f
#define LOG2E 1.4426950408889634f

typedef _Float16 f16x8 __attribute__((ext_vector_type(8)));
typedef float f32x4 __attribute__((ext_vector_type(4)));

#define MFMA(a, b, c) __builtin_amdgcn_mfma_f32_16x16x32_f16((a), (b), (c), 0, 0, 0)

__device__ __forceinline__ float lrelu(float x) { return fmaxf(x, SLOPE * x); }

__device__ __forceinline__ float fast_tanh(float x) {
    float e = exp2f(x * (2.0f * LOG2E));
    float r = __fdividef(1.0f, e + 1.0f);
    return fmaf(-2.0f, r, 1.0f);
}

__device__ __forceinline__ f16x8 cvt8(const float f[8]) {
    f16x8 r;
#pragma unroll
    for (int e = 0; e < 8; ++e) r[e] = (_Float16)f[e];
    return r;
}

__device__ __forceinline__ void split8(const float f[8], f16x8& hi, f16x8& lo) {
#pragma unroll
    for (int e = 0; e < 8; ++e) {
        _Float16 h = (_Float16)f[e];
        hi[e] = h;
        lo[e] = (_Float16)(f[e] - (float)h);
    }
}

// ---------------- prep: split weights into per-lane fp16 hi/lo fragments ----------------
__global__ __launch_bounds__(256) void pack_weights(
    const float* __restrict__ W0, const float* __restrict__ W2,
    const float* __restrict__ W3, _Float16* __restrict__ ws)
{
    const int g = blockIdx.x * 256 + threadIdx.x;   // fragment group id
    if (g >= 4608) return;

    const float* src;
    int ks, ct, lg, lr, ncol, kmax;
    long hoff, loff;
    if (g < 512) {                       // W0: [2][4][4][16]
        ks = g >> 8; ct = (g >> 6) & 3; lg = (g >> 4) & 3; lr = g & 15;
        src = W0; ncol = 64; kmax = 40;
        hoff = (long)g * 8;  loff = hoff + 4096;
    } else if (g < 2560) {               // W2: [4][8][4][16]
        int gg = g - 512;
        ks = gg >> 9; ct = (gg >> 6) & 7; lg = (gg >> 4) & 3; lr = gg & 15;
        src = W2; ncol = 128; kmax = 128;
        hoff = 8192 + (long)gg * 8; loff = hoff + 16384;
    } else {                             // W3: [4][8][4][16]
        int gg = g - 2560;
        ks = gg >> 9; ct = (gg >> 6) & 7; lg = (gg >> 4) & 3; lr = gg & 15;
        src = W3; ncol = 128; kmax = 128;
        hoff = 40960 + (long)gg * 8; loff = hoff + 16384;
    }

    f16x8 hi, lo;
#pragma unroll
    for (int e = 0; e < 8; ++e) {
        const int k = ks * 32 + lg * 8 + e;
        const float v = (k < kmax) ? src[(long)k * ncol + ct * 16 + lr] : 0.f;
        _Float16 h = (_Float16)v;
        hi[e] = h;
        lo[e] = (_Float16)(v - (float)h);
    }
    *reinterpret_cast<f16x8*>(ws + hoff) = hi;
    *reinterpret_cast<f16x8*>(ws + loff) = lo;
}

__global__ __launch_bounds__(128, 2) void critic_attention_kernel(
    const float* __restrict__ obs, const float* __restrict__ act,
    const float* __restrict__ b0, const float* __restrict__ W1,
    const float* __restrict__ b1v, const float* __restrict__ b2,
    const float* __restrict__ b3, const float* __restrict__ Wc,
    const float* __restrict__ bcv, const _Float16* __restrict__ ws,
    float* __restrict__ out)
{
    __shared__ float xcat[16 * 132];   // x_cat / x1, [item][128]; stride 132 = 16B-aligned
    __shared__ float part[16 * 68];    // wave1 partial xsum [item][64]
    __shared__ float ps[16];           // wave1 partial s per item
    __shared__ float vpart[32];        // Wc partials per wave

    const int t = threadIdx.x;
    const int lane = t & 63;
    const int w = t >> 6;              // wave 0/1
    const int lr = lane & 15;          // ITEM index (phase A, swapped D-col) / D-col (phase B)
    const int lg = lane >> 4;          // k-chunk / channel-row-group

    const long ibase = (long)blockIdx.x * 16;

    // W0 fragments (same content as before; now used as the A operand)
    f16x8 w0h[2][4], w0l[2][4];
#pragma unroll
    for (int ks = 0; ks < 2; ++ks)
#pragma unroll
        for (int cb = 0; cb < 4; ++cb) {
            const long o = (((long)(ks * 4 + cb) * 4 + lg) * 16 + lr) * 8;
            w0h[ks][cb] = *reinterpret_cast<const f16x8*>(ws + o);
            w0l[ks][cb] = *reinterpret_cast<const f16x8*>(ws + 4096 + o);
        }

    // per-lane channel constants: channel = cb*16 + lg*4 + j
    float b0c2[16], W1oc2[16], W1sc2[16];
#pragma unroll
    for (int cb = 0; cb < 4; ++cb)
#pragma unroll
        for (int j = 0; j < 4; ++j) {
            const int ch = cb * 16 + lg * 4 + j;
            b0c2[cb * 4 + j]  = b0[ch];
            W1sc2[cb * 4 + j] = W1[ch];
            W1oc2[cb * 4 + j] = W1[64 + ch];
        }
    const float b1s = b1v[0];

    const float* obase = obs + (ibase + lr) * 512 + lg * 8;   // item lr, feature block lg
    const float* abase = act + (ibase + lr) * 128;            // lg==0 lanes only

    const int abeg = w ? 8 : 1;        // wave0: agents 1..7; wave1: agents 8..15
    const int aend = w ? 16 : 8;

    float4 q0 = *reinterpret_cast<const float4*>(obase);
    float4 q1 = *reinterpret_cast<const float4*>(obase + 4);
    float4 c0 = make_float4(0.f, 0.f, 0.f, 0.f), c1 = c0;
    if (lg == 0) {
        c0 = *reinterpret_cast<const float4*>(abase);
        c1 = *reinterpret_cast<const float4*>(abase + 4);
    }

    // ---------------- agent 0: both waves (wave1 only needs a_self) ----------------
    float a_self, s, xsum[4][4];
    {
        float b0f[8] = {q0.x, q0.y, q0.z, q0.w, q1.x, q1.y, q1.z, q1.w};
        float b1f[8] = {c0.x, c0.y, c0.z, c0.w, c1.x, c1.y, c1.z, c1.w};
        f16x8 bi0 = cvt8(b0f);
        f16x8 bi1 = cvt8(b1f);

        // prefetch this wave's first loop agent
        q0 = *reinterpret_cast<const float4*>(obase + abeg * 32);
        q1 = *reinterpret_cast<const float4*>(obase + abeg * 32 + 4);
        if (lg == 0) {
            c0 = *reinterpret_cast<const float4*>(abase + abeg * 8);
            c1 = *reinterpret_cast<const float4*>(abase + abeg * 8 + 4);
        }

        f32x4 acc[4];
#pragma unroll
        for (int cb = 0; cb < 4; ++cb) {
            acc[cb] = (f32x4){b0c2[cb * 4 + 0], b0c2[cb * 4 + 1],
                              b0c2[cb * 4 + 2], b0c2[cb * 4 + 3]};   // bias folded
            acc[cb] = MFMA(w0l[0][cb], bi0, acc[cb]);   // swapped: weights = A
            acc[cb] = MFMA(w0h[0][cb], bi0, acc[cb]);
            acc[cb] = MFMA(w0l[1][cb], bi1, acc[cb]);
            acc[cb] = MFMA(w0h[1][cb], bi1, acc[cb]);
        }

        float xa[4][4], p = 0.f;
#pragma unroll
        for (int cb = 0; cb < 4; ++cb)
#pragma unroll
            for (int j = 0; j < 4; ++j) {
                xa[cb][j] = lrelu(acc[cb][j]);
                p = fmaf(xa[cb][j], W1sc2[cb * 4 + j], p);
            }
        p += __shfl_xor(p, 16, 64);    // sum partial dots across lg groups
        p += __shfl_xor(p, 32, 64);
        a_self = b1s + p;
        s = 0.f;
#pragma unroll
        for (int cb = 0; cb < 4; ++cb)
#pragma unroll
            for (int j = 0; j < 4; ++j) xsum[cb][j] = 0.f;

        if (w == 0) {
#pragma unroll
            for (int cb = 0; cb < 4; ++cb)
#pragma unroll
                for (int j = 0; j < 4; ++j)
                    xcat[lr * 132 + cb * 16 + lg * 4 + j] = xa[cb][j];   // x_self
        }
    }

    // ---------------- this wave's 7-8 "other" agents: no-max softmax ----------------
    for (int a = abeg; a < aend; ++a) {
        float b0f[8] = {q0.x, q0.y, q0.z, q0.w, q1.x, q1.y, q1.z, q1.w};
        float b1f[8] = {c0.x, c0.y, c0.z, c0.w, c1.x, c1.y, c1.z, c1.w};
        f16x8 bi0 = cvt8(b0f);
        f16x8 bi1 = cvt8(b1f);

        if (a + 1 < aend) {   // prefetch next agent
            q0 = *reinterpret_cast<const float4*>(obase + (a + 1) * 32);
            q1 = *reinterpret_cast<const float4*>(obase + (a + 1) * 32 + 4);
            if (lg == 0) {
                c0 = *reinterpret_cast<const float4*>(abase + (a + 1) * 8);
                c1 = *reinterpret_cast<const float4*>(abase + (a + 1) * 8 + 4);
            }
        }

        f32x4 acc[4];
#pragma unroll
        for (int cb = 0; cb < 4; ++cb) {
            acc[cb] = (f32x4){b0c2[cb * 4 + 0], b0c2[cb * 4 + 1],
                              b0c2[cb * 4 + 2], b0c2[cb * 4 + 3]};   // bias folded
            acc[cb] = MFMA(w0l[0][cb], bi0, acc[cb]);
            acc[cb] = MFMA(w0h[0][cb], bi0, acc[cb]);
            acc[cb] = MFMA(w0l[1][cb], bi1, acc[cb]);
            acc[cb] = MFMA(w0h[1][cb], bi1, acc[cb]);
        }

        float xa[4][4], p = 0.f;
#pragma unroll
        for (int cb = 0; cb < 4; ++cb)
#pragma unroll
            for (int j = 0; j < 4; ++j) {
                xa[cb][j] = fast_tanh(acc[cb][j]);
                p = fmaf(xa[cb][j], W1oc2[cb * 4 + j], p);
            }
        p += __shfl_xor(p, 16, 64);
        p += __shfl_xor(p, 32, 64);

        // bounded logits -> softmax without max-subtraction; ONE scalar per lane
        const float e = exp2f(lrelu(a_self + p) * LOG2E);
        s += e;
#pragma unroll
        for (int cb = 0; cb < 4; ++cb)
#pragma unroll
            for (int j = 0; j < 4; ++j)
                xsum[cb][j] = fmaf(e, xa[cb][j], xsum[cb][j]);
    }

    // ---------------- merge wave1 partials into wave0, write x_sum ----------------
    if (w == 1) {
#pragma unroll
        for (int cb = 0; cb < 4; ++cb)
#pragma unroll
            for (int j = 0; j < 4; ++j)
                part[lr * 68 + cb * 16 + lg * 4 + j] = xsum[cb][j];
        if (lg == 0) ps[lr] = s;
    }
    __syncthreads();
    if (w == 0) {
        const float stot = s + ps[lr];
        const float inv = __fdividef(1.f, stot);
#pragma unroll
        for (int cb = 0; cb < 4; ++cb)
#pragma unroll
            for (int j = 0; j < 4; ++j)
                xcat[lr * 132 + 64 + cb * 16 + lg * 4 + j] =
                    (xsum[cb][j] + part[lr * 68 + cb * 16 + lg * 4 + j]) * inv;
    }
    __syncthreads();

    // ---------------- phase B (unchanged r12): wave w owns cols [w*64, w*64+64) ----------------
    float b2c[4], b3c[4], Wcc[4];
#pragma unroll
    for (int ct = 0; ct < 4; ++ct) {
        const int ctg = w * 4 + ct;
        b2c[ct] = b2[ctg * 16 + lr];
        b3c[ct] = b3[ctg * 16 + lr];
        Wcc[ct] = Wc[ctg * 16 + lr];
    }
    const float bcs = bcv[0];

    f32x4 acc2[4];
#pragma unroll
    for (int ct = 0; ct < 4; ++ct)
        acc2[ct] = (f32x4){b2c[ct], b2c[ct], b2c[ct], b2c[ct]};   // bias folded
#pragma unroll
    for (int ks = 0; ks < 4; ++ks) {
        const float* xr = xcat + lr * 132 + ks * 32 + lg * 8;
        float4 r0 = *reinterpret_cast<const float4*>(xr);
        float4 r1 = *reinterpret_cast<const float4*>(xr + 4);
        float av[8] = {r0.x, r0.y, r0.z, r0.w, r1.x, r1.y, r1.z, r1.w};
        f16x8 ah, al;
        split8(av, ah, al);
#pragma unroll
        for (int ct = 0; ct < 4; ++ct) {
            const int ctg = w * 4 + ct;
            const long gg = ((long)(ks * 8 + ctg) * 4 + lg) * 16 + lr;
            f16x8 bh = *reinterpret_cast<const f16x8*>(ws + 8192 + gg * 8);
            f16x8 bl = *reinterpret_cast<const f16x8*>(ws + 24576 + gg * 8);
            acc2[ct] = MFMA(al, bh, acc2[ct]);
            acc2[ct] = MFMA(ah, bl, acc2[ct]);
            acc2[ct] = MFMA(ah, bh, acc2[ct]);
        }
    }
    __syncthreads();   // all x_cat reads done before x1 overwrite
#pragma unroll
    for (int ct = 0; ct < 4; ++ct)
#pragma unroll
        for (int j = 0; j < 4; ++j)
            xcat[(lg * 4 + j) * 132 + (w * 4 + ct) * 16 + lr] = lrelu(acc2[ct][j]);
    __syncthreads();

#pragma unroll
    for (int ct = 0; ct < 4; ++ct)
        acc2[ct] = (f32x4){b3c[ct], b3c[ct], b3c[ct], b3c[ct]};   // bias folded
#pragma unroll
    for (int ks = 0; ks < 4; ++ks) {
        const float* xr = xcat + lr * 132 + ks * 32 + lg * 8;
        float4 r0 = *reinterpret_cast<const float4*>(xr);
        float4 r1 = *reinterpret_cast<const float4*>(xr + 4);
        float av[8] = {r0.x, r0.y, r0.z, r0.w, r1.x, r1.y, r1.z, r1.w};
        f16x8 ah, al;
        split8(av, ah, al);
#pragma unroll
        for (int ct = 0; ct < 4; ++ct) {
            const int ctg = w * 4 + ct;
            const long gg = ((long)(ks * 8 + ctg) * 4 + lg) * 16 + lr;
            f16x8 bh = *reinterpret_cast<const f16x8*>(ws + 40960 + gg * 8);
            f16x8 bl = *reinterpret_cast<const f16x8*>(ws + 57344 + gg * 8);
            acc2[ct] = MFMA(al, bh, acc2[ct]);
            acc2[ct] = MFMA(ah, bl, acc2[ct]);
            acc2[ct] = MFMA(ah, bh, acc2[ct]);
        }
    }

    // value: per-lane partials over this wave's 64 cols, butterfly over lr
    float v[4];
#pragma unroll
    for (int j = 0; j < 4; ++j) {
        v[j] = lrelu(acc2[0][j]) * Wcc[0];
#pragma unroll
        for (int ct = 1; ct < 4; ++ct)
            v[j] = fmaf(lrelu(acc2[ct][j]), Wcc[ct], v[j]);
        v[j] += __shfl_xor(v[j], 1, 64);
        v[j] += __shfl_xor(v[j], 2, 64);
        v[j] += __shfl_xor(v[j], 4, 64);
        v[j] += __shfl_xor(v[j], 8, 64);
    }
    if (lr == 0) {
#pragma unroll
        for (int j = 0; j < 4; ++j)
            vpart[w * 16 + lg * 4 + j] = v[j];
    }
    __syncthreads();
    if (w == 0 && lr == 0) {
#pragma unroll
        for (int j = 0; j < 4; ++j) {
            const int row = lg * 4 + j;
            out[ibase + row] = vpart[row] + vpart[16 + row] + bcs;
        }
    }
}

extern "C" void kernel_launch(void* const* d_in, const int* in_sizes, int n_in,
                              void* d_out, int out_size, void* d_ws, size_t ws_size,
                              hipStream_t stream) {
    (void)in_sizes; (void)n_in; (void)ws_size; (void)out_size;
    const float* obs = (const float*)d_in[0];
    const float* act = (const float*)d_in[1];
    const float* W0  = (const float*)d_in[2];
    const float* b0  = (const float*)d_in[3];
    const float* W1  = (const float*)d_in[4];
    const float* b1  = (const float*)d_in[5];
    const float* W2  = (const float*)d_in[6];
    const float* b2  = (const float*)d_in[7];
    const float* W3  = (const float*)d_in[8];
    const float* b3  = (const float*)d_in[9];
    const float* Wc  = (const float*)d_in[10];
    const float* bc  = (const float*)d_in[11];
    _Float16* ws = (_Float16*)d_ws;

    pack_weights<<<dim3(18), dim3(256), 0, stream>>>(W0, W2, W3, ws);
    critic_attention_kernel<<<dim3(65536 / 16), dim3(128), 0, stream>>>(
        obs, act, b0, W1, b1, b2, b3, Wc, bc, ws, (float*)d_out);
}